// Round 1
// baseline (378.585 us; speedup 1.0000x reference)
//
#include <hip/hip_runtime.h>
#include <math.h>

// Problem constants
#define Bdim 16
#define Cdim 32
#define Ndim 207
#define CINd 64
#define COUTd 64

// strides (floats)
#define X_B (Cdim * Ndim * CINd)            // 423936
#define X_C (Ndim * CINd)                   // 13248
#define W_C (Ndim * CINd * COUTd * 2)       // 1695744
#define W_N (CINd * COUTd * 2)              // 8192

// 1/sqrt(1+1e-5)
#define BN_EVAL 0.9999950000374997f

__global__ __launch_bounds__(256, 4)
void fused_multilinear(const float* __restrict__ x,
                       const float* __restrict__ rw,   // res_weight
                       const float* __restrict__ rb,   // res_bias [C*N]
                       const float* __restrict__ mw,   // mlp_w [COUT][CIN]
                       const float* __restrict__ mb,   // mlp_b [COUT]
                       const float* __restrict__ gw,   // gate_w [COUT][CIN]
                       const float* __restrict__ gb,   // gate_b [COUT]
                       const float* __restrict__ ow,   // order_w [2]
                       const float* __restrict__ obp,  // order_b [1]
                       float* __restrict__ out)
{
    // mg[i][o] = {mlp_w[o][i], gate_w[o][i]}, row stride 65 float2 (pad)
    __shared__ float2 mg[64 * 65];

    const int cn = blockIdx.x;
    const int c  = cn / Ndim;
    const int n  = cn % Ndim;
    const int o  = threadIdx.x & 63;
    // wave-uniform batch-group: wave w handles b = 4w .. 4w+3
    const int bg = __builtin_amdgcn_readfirstlane((int)(threadIdx.x >> 6));

    // --- stage mlp_w/gate_w transposed into LDS (coalesced global reads) ---
    for (int t = threadIdx.x; t < 4096; t += 256) {
        const int oo = t >> 6;       // row of mw/gw
        const int ii = t & 63;       // col
        mg[ii * 65 + oo] = make_float2(mw[t], gw[t]);
    }
    __syncthreads();

    // per-block bases
    const float* wbase = rw + (size_t)c * W_C + (size_t)n * W_N + (size_t)(o * 2);
    const float* xb0   = x + (size_t)c * X_C + (size_t)(n * CINd);

    const float* xr[4];
#pragma unroll
    for (int j = 0; j < 4; ++j)
        xr[j] = xb0 + (size_t)(bg * 4 + j) * X_B;

    float acc0[4] = {0.f, 0.f, 0.f, 0.f};   // sum_i x * W[i][o][0]
    float acc1[4] = {0.f, 0.f, 0.f, 0.f};   // sum_i x^2 * W[i][o][1]  (BN folded later)
    float accS[4] = {0.f, 0.f, 0.f, 0.f};   // mlp branch
    float accG[4] = {0.f, 0.f, 0.f, 0.f};   // gate branch

    for (int i0 = 0; i0 < 64; i0 += 8) {
        // wave-uniform x chunk: 4 batches x 8 i  (scalar-friendly loads)
        float xv[4][8];
#pragma unroll
        for (int j = 0; j < 4; ++j) {
            const float4 a  = *(const float4*)(xr[j] + i0);
            const float4 b4 = *(const float4*)(xr[j] + i0 + 4);
            xv[j][0] = a.x;  xv[j][1] = a.y;  xv[j][2] = a.z;  xv[j][3] = a.w;
            xv[j][4] = b4.x; xv[j][5] = b4.y; xv[j][6] = b4.z; xv[j][7] = b4.w;
        }
#pragma unroll
        for (int k = 0; k < 8; ++k) {
            const int i = i0 + k;
            const float2 w = *(const float2*)(wbase + (size_t)i * 128); // W[i][o][0..1]
            const float2 m = mg[i * 65 + o];
#pragma unroll
            for (int j = 0; j < 4; ++j) {
                const float xb = xv[j][k];
                acc0[j] = __builtin_fmaf(xb, w.x, acc0[j]);
                const float t = xb * w.y;
                acc1[j] = __builtin_fmaf(xb, t, acc1[j]);
                accS[j] = __builtin_fmaf(xb, m.x, accS[j]);
                accG[j] = __builtin_fmaf(xb, m.y, accG[j]);
            }
        }
    }

    // --- epilogue ---
    const float rbias = rb[c * Ndim + n];
    const float ow0 = ow[0], ow1 = ow[1], obias = obp[0];
    const float mbias = mb[o];
    const float gbias = gb[o];

#pragma unroll
    for (int j = 0; j < 4; ++j) {
        const int b = bg * 4 + j;
        // order combine: sum_d (acc_d + res_bias)*order_w[d] + order_b, then * SCALE/4
        float uniq = (acc0[j] + rbias) * ow0
                   + (BN_EVAL * acc1[j] + rbias) * ow1
                   + obias;
        uniq *= 0.125f;  // SCALE/4 = (64/(2*64))/4

        const float xs = accS[j] + mbias;
        const float zg = accG[j] + gbias;
        const float g  = 1.0f / (1.0f + __expf(-zg));

        const size_t idx = (size_t)b * X_B + (size_t)c * X_C + (size_t)(n * CINd) + o;
        out[idx] = g * uniq + (1.0f - g) * xs + x[idx];
    }
}

extern "C" void kernel_launch(void* const* d_in, const int* in_sizes, int n_in,
                              void* d_out, int out_size, void* d_ws, size_t ws_size,
                              hipStream_t stream)
{
    const float* x   = (const float*)d_in[0];
    const float* rw  = (const float*)d_in[1];
    const float* rb  = (const float*)d_in[2];
    const float* mw  = (const float*)d_in[3];
    const float* mb  = (const float*)d_in[4];
    const float* gw  = (const float*)d_in[5];
    const float* gb  = (const float*)d_in[6];
    const float* ow  = (const float*)d_in[7];
    const float* ob  = (const float*)d_in[8];
    float* out = (float*)d_out;

    fused_multilinear<<<dim3(Cdim * Ndim), dim3(256), 0, stream>>>(
        x, rw, rb, mw, mb, gw, gb, ow, ob, out);
}